// Round 16
// baseline (151.390 us; speedup 1.0000x reference)
//
#include <hip/hip_runtime.h>
#include <cmath>

#define D_MODEL  1024
#define NHEADS   16
#define DHEAD    64
#define BATCH    2
#define SEQ      2048
#define MROWS    (BATCH * SEQ)
#define HALF_DH  32
#define BHTOT    (BATCH * NHEADS)          // 32
#define QROWS    (BHTOT * SEQ)             // 65536
#define LDK      68                        // padded LDS row (shorts): 136B breaks bank alignment

// softmax scale baked into Q at projection time: S' = (Q*SCQ)K^T is directly
// the exp2 argument;  exp2(S' - m') == softmax numerator (shift-invariant).
#define SCQ (0.125f * 1.44269504088896340736f)

typedef __attribute__((ext_vector_type(8))) short short8;    // 8 bf16 = 4 VGPRs
typedef __attribute__((ext_vector_type(4))) float f32x4;     // 16x16 C/D
typedef __attribute__((ext_vector_type(16))) float f32x16;   // 32x32 C/D

#define MFMA16(A,B,C) __builtin_amdgcn_mfma_f32_16x16x32_bf16(A,B,C,0,0,0)
#define MFMA32(A,B,C) __builtin_amdgcn_mfma_f32_32x32x16_bf16(A,B,C,0,0,0)

__device__ __forceinline__ unsigned short f2bf(float f) {
    unsigned int u = __float_as_uint(f);
    u += 0x7fffu + ((u >> 16) & 1u);
    return (unsigned short)(u >> 16);
}

__device__ __forceinline__ void gload_lds16(const void* g, void* l) {
    __builtin_amdgcn_global_load_lds(
        (const __attribute__((address_space(1))) unsigned int*)g,
        (__attribute__((address_space(3))) unsigned int*)l,
        16, 0, 0);
}

// ---------------------------------------------------------------------------
// K0: fused prep — blockIdx.x ranges (block-uniform branches):
//   [0,4096): x fp32->bf16 | [4096,5120): weight transpose | [5120,5376): RoPE
// ---------------------------------------------------------------------------
__global__ __launch_bounds__(256)
void prep_kernel(const float* __restrict__ x,
                 const float* __restrict__ Wq, const float* __restrict__ Wk,
                 const float* __restrict__ Wv, const float* __restrict__ Wo,
                 unsigned short* __restrict__ xb,
                 unsigned short* __restrict__ wqT, unsigned short* __restrict__ wkT,
                 unsigned short* __restrict__ wvT, unsigned short* __restrict__ woT,
                 float* __restrict__ cosT, float* __restrict__ sinT)
{
    __shared__ unsigned short T[64][68];
    const int bid = blockIdx.x;
    const int tid = threadIdx.x;

    if (bid < 4096) {                       // convert x -> bf16
        int i = bid * 256 + tid;
        float4 v = ((const float4*)x)[i];
        ushort4 o;
        o.x = f2bf(v.x); o.y = f2bf(v.y); o.z = f2bf(v.z); o.w = f2bf(v.w);
        ((ushort4*)xb)[i] = o;
    } else if (bid < 5120) {                // weight transpose
        int b2 = bid - 4096;
        int z  = b2 >> 8;
        int bx = (b2 & 255) >> 4;
        int by = b2 & 15;
        const float* W; unsigned short* Wt;
        switch (z) {
            case 0:  W = Wq; Wt = wqT; break;
            case 1:  W = Wk; Wt = wkT; break;
            case 2:  W = Wv; Wt = wvT; break;
            default: W = Wo; Wt = woT; break;
        }
        const int k0 = bx * 64, n0 = by * 64;
        const int r = tid >> 4, cq = tid & 15;
        #pragma unroll
        for (int p = 0; p < 4; ++p) {
            int kk = r + 16 * p;
            float4 vv = *(const float4*)&W[(size_t)(k0 + kk) * D_MODEL + n0 + cq * 4];
            T[cq * 4 + 0][kk] = f2bf(vv.x);
            T[cq * 4 + 1][kk] = f2bf(vv.y);
            T[cq * 4 + 2][kk] = f2bf(vv.z);
            T[cq * 4 + 3][kk] = f2bf(vv.w);
        }
        __syncthreads();
        #pragma unroll
        for (int p = 0; p < 4; ++p) {
            int n = r + 16 * p;
            ushort4 ov;
            ov.x = T[n][cq * 4 + 0]; ov.y = T[n][cq * 4 + 1];
            ov.z = T[n][cq * 4 + 2]; ov.w = T[n][cq * 4 + 3];
            *(ushort4*)&Wt[(size_t)(n0 + n) * D_MODEL + k0 + cq * 4] = ov;
        }
    } else {                                // RoPE tables
        int idx = (bid - 5120) * 256 + tid;
        int l = idx >> 5;
        int j = idx & 31;
        float inv = powf(10000.0f, -(float)(2 * j) / (float)DHEAD);
        float ang = (float)l * inv;
        cosT[idx] = cosf(ang);
        sinT[idx] = sinf(ang);
    }
}

// ---------------------------------------------------------------------------
// K3: fused QKV projection, BM=128 BN=64 BK=64 (R10/R12-proven tile).
// blockIdx.z: 0=q (RoPE, pre-scaled by SCQ), 1=k (RoPE),
//             2=v (LDS-transpose -> Vt[bh][d][l]).
// ---------------------------------------------------------------------------
__global__ __launch_bounds__(256)
void qkv_proj_kernel(const unsigned short* __restrict__ A,
                     const unsigned short* __restrict__ wqT, const unsigned short* __restrict__ wkT,
                     const unsigned short* __restrict__ wvT,
                     const float* __restrict__ bq, const float* __restrict__ bk,
                     const float* __restrict__ bv,
                     const float* __restrict__ cosT, const float* __restrict__ sinT,
                     unsigned short* __restrict__ qb, unsigned short* __restrict__ kb,
                     unsigned short* __restrict__ vtb)
{
    __shared__ unsigned short SMEM[128 * 64 + 64 * 64];   // As(16KB) + Bs(8KB)
    unsigned short* As = SMEM;
    unsigned short* Bs = SMEM + 128 * 64;

    const int z = blockIdx.z;
    const unsigned short* Bt = (z == 0) ? wqT : (z == 1) ? wkT : wvT;
    const float* bias = (z == 0) ? bq : (z == 1) ? bk : bv;

    const int tid = threadIdx.x;
    const int w = tid >> 6, ln = tid & 63;
    const int c = ln & 15, g = ln >> 4;
    const int bm = blockIdx.x * 128, bn = blockIdx.y * 64;
    const int srow = ln >> 3, sblk = ln & 7;

    f32x4 acc[2][4];
    #pragma unroll
    for (int mi = 0; mi < 2; ++mi)
        #pragma unroll
        for (int ni = 0; ni < 4; ++ni) acc[mi][ni] = (f32x4){0.f, 0.f, 0.f, 0.f};

    for (int k0 = 0; k0 < D_MODEL; k0 += 64) {
        __syncthreads();
        #pragma unroll
        for (int i = 0; i < 4; ++i) {
            int chunk = w * 4 + i;
            int row = chunk * 8 + srow;
            int gcol = (sblk ^ (row & 7)) * 8;
            gload_lds16(&A[(size_t)(bm + row) * D_MODEL + k0 + gcol], &As[chunk * 512]);
        }
        #pragma unroll
        for (int i = 0; i < 2; ++i) {
            int chunk = w * 2 + i;
            int row = chunk * 8 + srow;
            int gcol = (sblk ^ (row & 7)) * 8;
            gload_lds16(&Bt[(size_t)(bn + row) * D_MODEL + k0 + gcol], &Bs[chunk * 512]);
        }
        __syncthreads();

        #pragma unroll
        for (int ks = 0; ks < 2; ++ks) {
            const int koff = (ks * 32 + g * 8) ^ ((c & 7) * 8);
            short8 af[2];
            #pragma unroll
            for (int mi = 0; mi < 2; ++mi)
                af[mi] = *(const short8*)&As[(w * 32 + mi * 16 + c) * 64 + koff];
            #pragma unroll
            for (int ni = 0; ni < 4; ++ni) {
                short8 bfr = *(const short8*)&Bs[(ni * 16 + c) * 64 + koff];
                #pragma unroll
                for (int mi = 0; mi < 2; ++mi)
                    acc[mi][ni] = MFMA16(af[mi], bfr, acc[mi][ni]);
            }
        }
    }

    float bv4[4];
    #pragma unroll
    for (int ni = 0; ni < 4; ++ni) bv4[ni] = bias[bn + ni * 16 + c];

    if (z < 2) {
        unsigned short* op = z ? kb : qb;
        const float qscale = (z == 0) ? SCQ : 1.0f;   // bake softmax scale into q
        const int hy = blockIdx.y;                    // head (BN == DHEAD)
        #pragma unroll
        for (int mi = 0; mi < 2; ++mi) {
            #pragma unroll
            for (int r = 0; r < 4; ++r) {
                const int m = bm + w * 32 + mi * 16 + g * 4 + r;
                const int b = m >> 11, ll = m & (SEQ - 1);
                float v[4];
                #pragma unroll
                for (int ni = 0; ni < 4; ++ni) v[ni] = acc[mi][ni][r] + bv4[ni];
                #pragma unroll
                for (int ni = 0; ni < 2; ++ni) {      // RoPE
                    int d = ni * 16 + c;
                    float co = cosT[ll * HALF_DH + d];
                    float si = sinT[ll * HALF_DH + d];
                    float lo = v[ni], hi = v[ni + 2];
                    v[ni]     = lo * co - hi * si;
                    v[ni + 2] = hi * co + lo * si;
                }
                unsigned short* dst = op + ((size_t)(b * NHEADS + hy) * SEQ + ll) * DHEAD;
                #pragma unroll
                for (int ni = 0; ni < 4; ++ni) dst[ni * 16 + c] = f2bf(v[ni] * qscale);
            }
        }
    } else {
        // v: transpose 128(m) x 64(d) tile -> Vt[bh][d][l] via LDS (overlay SMEM)
        unsigned short (*T)[136] = (unsigned short(*)[136])SMEM;   // 64 x 136 shorts
        __syncthreads();                               // all MFMA LDS reads done
        #pragma unroll
        for (int mi = 0; mi < 2; ++mi)
            #pragma unroll
            for (int r = 0; r < 4; ++r)
                #pragma unroll
                for (int ni = 0; ni < 4; ++ni)
                    T[ni * 16 + c][w * 32 + mi * 16 + g * 4 + r] = f2bf(acc[mi][ni][r] + bv4[ni]);
        __syncthreads();
        const int b  = bm >> 11;
        const int l0 = bm & (SEQ - 1);                 // per-batch seq offset
        const int bh = b * NHEADS + blockIdx.y;
        unsigned short* Vo = vtb + (size_t)bh * DHEAD * SEQ;
        #pragma unroll
        for (int it = 0; it < 4; ++it) {
            int row  = (tid >> 4) + it * 16;           // d
            int col8 = tid & 15;                       // 8-short chunk along m
            uint4 val = *(const uint4*)&T[row][col8 * 8];
            *(uint4*)&Vo[(size_t)row * SEQ + l0 + col8 * 8] = val;
        }
    }
}

// ---------------------------------------------------------------------------
// K4: out-projection GEMM, BM=128 BN=64 (bf16 A=ob, fp32 out) (R10-proven)
// ---------------------------------------------------------------------------
__global__ __launch_bounds__(256)
void outproj_kernel(const unsigned short* __restrict__ A, const unsigned short* __restrict__ Bt,
                    const float* __restrict__ bias, float* __restrict__ out)
{
    __shared__ unsigned short As[128 * 64];
    __shared__ unsigned short Bs[64 * 64];
    const int tid = threadIdx.x;
    const int w = tid >> 6, ln = tid & 63;
    const int c = ln & 15, g = ln >> 4;
    const int bm = blockIdx.x * 128, bn = blockIdx.y * 64;
    const int srow = ln >> 3, sblk = ln & 7;

    f32x4 acc[2][4];
    #pragma unroll
    for (int mi = 0; mi < 2; ++mi)
        #pragma unroll
        for (int ni = 0; ni < 4; ++ni) acc[mi][ni] = (f32x4){0.f, 0.f, 0.f, 0.f};

    for (int k0 = 0; k0 < D_MODEL; k0 += 64) {
        __syncthreads();
        #pragma unroll
        for (int i = 0; i < 4; ++i) {
            int chunk = w * 4 + i;
            int row = chunk * 8 + srow;
            int gcol = (sblk ^ (row & 7)) * 8;
            gload_lds16(&A[(size_t)(bm + row) * D_MODEL + k0 + gcol], &As[chunk * 512]);
        }
        #pragma unroll
        for (int i = 0; i < 2; ++i) {
            int chunk = w * 2 + i;
            int row = chunk * 8 + srow;
            int gcol = (sblk ^ (row & 7)) * 8;
            gload_lds16(&Bt[(size_t)(bn + row) * D_MODEL + k0 + gcol], &Bs[chunk * 512]);
        }
        __syncthreads();

        #pragma unroll
        for (int ks = 0; ks < 2; ++ks) {
            const int koff = (ks * 32 + g * 8) ^ ((c & 7) * 8);
            short8 af[2];
            #pragma unroll
            for (int mi = 0; mi < 2; ++mi)
                af[mi] = *(const short8*)&As[(w * 32 + mi * 16 + c) * 64 + koff];
            #pragma unroll
            for (int ni = 0; ni < 4; ++ni) {
                short8 bfr = *(const short8*)&Bs[(ni * 16 + c) * 64 + koff];
                #pragma unroll
                for (int mi = 0; mi < 2; ++mi)
                    acc[mi][ni] = MFMA16(af[mi], bfr, acc[mi][ni]);
            }
        }
    }

    float bv4[4];
    #pragma unroll
    for (int ni = 0; ni < 4; ++ni) bv4[ni] = bias[bn + ni * 16 + c];
    #pragma unroll
    for (int mi = 0; mi < 2; ++mi)
        #pragma unroll
        for (int r = 0; r < 4; ++r) {
            const int m = bm + w * 32 + mi * 16 + g * 4 + r;
            #pragma unroll
            for (int ni = 0; ni < 4; ++ni)
                out[(size_t)m * D_MODEL + bn + ni * 16 + c] = acc[mi][ni][r] + bv4[ni];
        }
}

// ---------------------------------------------------------------------------
// K5: MFMA flash attention (R13 body) with REG-STAGED K/V into padded LDS
// (LDK=68 shorts/row, 136B): fragment reads become 2-way bank-aliased (free)
// instead of the structural 4-way under global_load_lds's linear chunks.
// T14 order: issue next-tile global loads at loop top (latency hides under
// QK^T+softmax), ds_write to buf^1 after softmax (buf^1 readers finished
// before the last barrier). Numerically identical to R13.
// ---------------------------------------------------------------------------
__global__ __launch_bounds__(256, 4)
void attn_mfma32_kernel(const unsigned short* __restrict__ Q, const unsigned short* __restrict__ K,
                        const unsigned short* __restrict__ Vt, unsigned short* __restrict__ O,
                        float* __restrict__ accP, float* __restrict__ ml, int nsplit)
{
    __shared__ unsigned short Ks[2][64 * LDK];
    __shared__ unsigned short Vs[2][64 * LDK];
    const int tid = threadIdx.x;
    const int w = tid >> 6, ln = tid & 63;
    const int ql = ln & 31;
    const int h  = ln >> 5;
    const int bh = blockIdx.y;
    const int q  = blockIdx.x * 128 + w * 32 + ql;
    const int split = blockIdx.z;
    const int ntile = SEQ / (64 * nsplit);
    const int kt0 = split * (SEQ / nsplit);

    // staging role: lane ln loads rows srow0+8i (i=0,1), 16B at col scol
    const int srow0 = 16 * w + (ln >> 3);
    const int scol  = (ln & 7) * 8;

    const unsigned short* Qb = Q  + (size_t)bh * SEQ * DHEAD;
    const unsigned short* Kb = K  + (size_t)bh * SEQ * DHEAD;
    const unsigned short* Vb = Vt + (size_t)bh * DHEAD * SEQ;

    short8 qf[4];
    #pragma unroll
    for (int dk = 0; dk < 4; ++dk)
        qf[dk] = *(const short8*)&Qb[(size_t)q * DHEAD + dk * 16 + h * 8];

    short8 onesF;
    #pragma unroll
    for (int i = 0; i < 8; ++i) onesF[i] = (short)0x3F80;

    const int rA = ql * LDK, rB = (32 + ql) * LDK;

    f32x16 accO0, accO1, accS;
    #pragma unroll
    for (int r = 0; r < 16; ++r) { accO0[r] = 0.f; accO1[r] = 0.f; accS[r] = 0.f; }
    float mst = -1e30f;

    // prologue: tile 0 -> regs -> buf 0
    short8 kreg[2], vreg[2];
    #pragma unroll
    for (int i = 0; i < 2; ++i) {
        int row = srow0 + 8 * i;
        kreg[i] = *(const short8*)&Kb[(size_t)(kt0 + row) * DHEAD + scol];
        vreg[i] = *(const short8*)&Vb[(size_t)row * SEQ + kt0 + scol];
    }
    #pragma unroll
    for (int i = 0; i < 2; ++i) {
        int row = srow0 + 8 * i;
        *(short8*)&Ks[0][row * LDK + scol] = kreg[i];
        *(short8*)&Vs[0][row * LDK + scol] = vreg[i];
    }
    __syncthreads();

    int cur = 0;
    for (int it = 0; it < ntile; ++it) {
        const int kt = kt0 + it * 64;
        // issue next-tile global loads (latency hidden under QK^T + softmax)
        if (it + 1 < ntile) {
            #pragma unroll
            for (int i = 0; i < 2; ++i) {
                int row = srow0 + 8 * i;
                kreg[i] = *(const short8*)&Kb[(size_t)(kt + 64 + row) * DHEAD + scol];
                vreg[i] = *(const short8*)&Vb[(size_t)row * SEQ + kt + 64 + scol];
            }
        }

        // S = K Q^T   (already in exp2-argument units)
        f32x16 s0, s1;
        #pragma unroll
        for (int r = 0; r < 16; ++r) { s0[r] = 0.f; s1[r] = 0.f; }
        #pragma unroll
        for (int dk = 0; dk < 4; ++dk) {
            short8 kf0 = *(const short8*)&Ks[cur][rA + (2 * dk + h) * 8];
            short8 kf1 = *(const short8*)&Ks[cur][rB + (2 * dk + h) * 8];
            s0 = MFMA32(kf0, qf[dk], s0);
            s1 = MFMA32(kf1, qf[dk], s1);
        }

        // row max: max3-fused triplet tree + one cross-half shfl
        float a0 = fmaxf(fmaxf(s0[0], s0[1]), s0[2]);
        float a1 = fmaxf(fmaxf(s0[3], s0[4]), s0[5]);
        float a2 = fmaxf(fmaxf(s0[6], s0[7]), s0[8]);
        float a3 = fmaxf(fmaxf(s0[9], s0[10]), s0[11]);
        float a4 = fmaxf(fmaxf(s0[12], s0[13]), s0[14]);
        float a5 = fmaxf(fmaxf(s0[15], s1[0]), s1[1]);
        float a6 = fmaxf(fmaxf(s1[2], s1[3]), s1[4]);
        float a7 = fmaxf(fmaxf(s1[5], s1[6]), s1[7]);
        float a8 = fmaxf(fmaxf(s1[8], s1[9]), s1[10]);
        float a9 = fmaxf(fmaxf(s1[11], s1[12]), s1[13]);
        float aA = fmaxf(s1[14], s1[15]);
        float b0 = fmaxf(fmaxf(a0, a1), a2);
        float b1 = fmaxf(fmaxf(a3, a4), a5);
        float b2 = fmaxf(fmaxf(a6, a7), a8);
        float b3 = fmaxf(a9, aA);
        float mx = fmaxf(fmaxf(fmaxf(b0, b1), b2), b3);
        mx = fmaxf(mx, __shfl_xor(mx, 32));

        // T13 defer-max: rescale only if some lane's growth exceeds THR
        if (!__all(mx - mst <= 4.0f)) {
            const float mn = fmaxf(mst, mx);
            const float rsc = exp2f(mst - mn);
            #pragma unroll
            for (int r = 0; r < 16; ++r) { accO0[r] *= rsc; accO1[r] *= rsc; }
            accS[0] *= rsc;
            mst = mn;
        }

        // P = exp2(S - mst)
        #pragma unroll
        for (int r = 0; r < 16; ++r) {
            s0[r] = exp2f(s0[r] - mst);
            s1[r] = exp2f(s1[r] - mst);
        }

        // write staged next-tile regs to buf^1 (safe since last barrier)
        if (it + 1 < ntile) {
            #pragma unroll
            for (int i = 0; i < 2; ++i) {
                int row = srow0 + 8 * i;
                *(short8*)&Ks[cur ^ 1][row * LDK + scol] = kreg[i];
                *(short8*)&Vs[cur ^ 1][row * LDK + scol] = vreg[i];
            }
        }

        // repack P -> 4 bf16 B-fragments (cvt_pk + permlane32_swap, verified R5)
        short8 pf[4];
        #define REPACK_T(T, SV)                                                          \
        {                                                                                \
            unsigned int wA0, wA1, wB0, wB1;                                             \
            asm("v_cvt_pk_bf16_f32 %0, %1, %2" : "=v"(wA0)                               \
                : "v"((SV)[8 * ((T) & 1) + 0]), "v"((SV)[8 * ((T) & 1) + 1]));           \
            asm("v_cvt_pk_bf16_f32 %0, %1, %2" : "=v"(wA1)                               \
                : "v"((SV)[8 * ((T) & 1) + 2]), "v"((SV)[8 * ((T) & 1) + 3]));           \
            asm("v_cvt_pk_bf16_f32 %0, %1, %2" : "=v"(wB0)                               \
                : "v"((SV)[8 * ((T) & 1) + 4]), "v"((SV)[8 * ((T) & 1) + 5]));           \
            asm("v_cvt_pk_bf16_f32 %0, %1, %2" : "=v"(wB1)                               \
                : "v"((SV)[8 * ((T) & 1) + 6]), "v"((SV)[8 * ((T) & 1) + 7]));           \
            asm("v_permlane32_swap_b32 %0, %1" : "+v"(wA0), "+v"(wB0));                  \
            asm("v_permlane32_swap_b32 %0, %1" : "+v"(wA1), "+v"(wB1));                  \
            union { short8 v; unsigned int u[4]; } tmp;                                  \
            tmp.u[0] = wA0; tmp.u[1] = wA1; tmp.u[2] = wB0; tmp.u[3] = wB1;              \
            pf[T] = tmp.v;                                                               \
        }
        REPACK_T(0, s0) REPACK_T(1, s0) REPACK_T(2, s1) REPACK_T(3, s1)
        #undef REPACK_T

        // O^T += V^T P, and row-sums via ones-A MFMA (accS[0] = l)
        #pragma unroll
        for (int t = 0; t < 4; ++t) {
            short8 vf0 = *(const short8*)&Vs[cur][rA + (2 * t + h) * 8];
            short8 vf1 = *(const short8*)&Vs[cur][rB + (2 * t + h) * 8];
            accS  = MFMA32(onesF, pf[t], accS);
            accO0 = MFMA32(vf0, pf[t], accO0);
            accO1 = MFMA32(vf1, pf[t], accO1);
        }

        __syncthreads();
        cur ^= 1;
    }

    const float accL = accS[0];
    if (nsplit == 1) {
        const int b = bh >> 4, hh = bh & 15;
        const float inv = 1.0f / accL;
        unsigned short* dst = O + ((size_t)(b * SEQ + q)) * D_MODEL + hh * DHEAD;
        #define EPI(ACC, DC)                                                             \
        {                                                                                \
            _Pragma("unroll")                                                            \
            for (int rq = 0; rq < 4; ++rq) {                                             \
                float a0 = (ACC)[4 * rq + 0] * inv, a1 = (ACC)[4 * rq + 1] * inv;        \
                float a2 = (ACC)[4 * rq + 2] * inv, a3 = (ACC)[4 * rq + 3] * inv;        \
                unsigned int p0, p1;                                                     \
                asm("v_cvt_pk_bf16_f32 %0, %1, %2" : "=v"(p0) : "v"(a0), "v"(a1));       \
                asm("v_cvt_pk_bf16_f32 %0, %1, %2" : "=v"(p1) : "v"(a2), "v"(a3));       \
                uint2 pk; pk.x = p0; pk.y = p1;                                          \
                *(uint2*)(dst + 32 * (DC) + 8 * rq + 4 * h) = pk;                        \
            }                                                                            \
        }
        EPI(accO0, 0) EPI(accO1, 1)
        #undef EPI
    } else {
        float* base = accP + ((size_t)(split * BHTOT + bh) * SEQ + q) * 64;
        #pragma unroll
        for (int rq = 0; rq < 4; ++rq) {
            float4 v0, v1;
            v0.x = accO0[4 * rq + 0]; v0.y = accO0[4 * rq + 1];
            v0.z = accO0[4 * rq + 2]; v0.w = accO0[4 * rq + 3];
            v1.x = accO1[4 * rq + 0]; v1.y = accO1[4 * rq + 1];
            v1.z = accO1[4 * rq + 2]; v1.w = accO1[4 * rq + 3];
            *(float4*)&base[8 * rq + 4 * h]      = v0;
            *(float4*)&base[32 + 8 * rq + 4 * h] = v1;
        }
        if (h == 0) {
            float2 v; v.x = mst; v.y = accL;
            ((float2*)ml)[(size_t)(split * BHTOT + bh) * SEQ + q] = v;
        }
    }
}

// ---------------------------------------------------------------------------
// K6: combine the 2 split-K partials (exact fp32 online-softmax merge;
// m values are already exp2-argument units — no SC)
// ---------------------------------------------------------------------------
__global__ __launch_bounds__(256)
void combine2_kernel(const float* __restrict__ accP, const float* __restrict__ ml,
                     unsigned short* __restrict__ ob)
{
    int t = blockIdx.x * 256 + threadIdx.x;        // over QROWS*16
    int d4  = (t & 15) * 4;
    int bhq = t >> 4;
    const float2* ML = (const float2*)ml;
    float2 m0 = ML[bhq];
    float2 m1 = ML[(size_t)QROWS + bhq];
    float M  = fmaxf(m0.x, m1.x);
    float w0 = exp2f(m0.x - M);
    float w1 = exp2f(m1.x - M);
    float inv = 1.0f / (w0 * m0.y + w1 * m1.y);
    float4 a0 = *(const float4*)&accP[(size_t)bhq * 64 + d4];
    float4 a1 = *(const float4*)&accP[(size_t)QROWS * 64 + (size_t)bhq * 64 + d4];
    float o0 = (a0.x * w0 + a1.x * w1) * inv;
    float o1 = (a0.y * w0 + a1.y * w1) * inv;
    float o2 = (a0.z * w0 + a1.z * w1) * inv;
    float o3 = (a0.w * w0 + a1.w * w1) * inv;
    int bh = bhq >> 11, q = bhq & (SEQ - 1);
    int b = bh >> 4, hh = bh & 15;
    ushort4 ov;
    ov.x = f2bf(o0); ov.y = f2bf(o1); ov.z = f2bf(o2); ov.w = f2bf(o3);
    *(ushort4*)&ob[((size_t)(b * SEQ + q)) * D_MODEL + hh * DHEAD + d4] = ov;
}

// ---------------------------------------------------------------------------
extern "C" void kernel_launch(void* const* d_in, const int* in_sizes, int n_in,
                              void* d_out, int out_size, void* d_ws, size_t ws_size,
                              hipStream_t stream)
{
    const float* x  = (const float*)d_in[0];
    const float* Wq = (const float*)d_in[1];
    const float* bq = (const float*)d_in[2];
    const float* Wk = (const float*)d_in[3];
    const float* bk = (const float*)d_in[4];
    const float* Wv = (const float*)d_in[5];
    const float* bv = (const float*)d_in[6];
    const float* Wo = (const float*)d_in[7];
    const float* bo = (const float*)d_in[8];

    // workspace carve
    char* p = (char*)d_ws;
    float* cosT = (float*)p;            p += (size_t)SEQ * HALF_DH * 4;
    float* sinT = (float*)p;            p += (size_t)SEQ * HALF_DH * 4;
    unsigned short* xb  = (unsigned short*)p; p += (size_t)MROWS * D_MODEL * 2;
    unsigned short* wqT = (unsigned short*)p; p += (size_t)D_MODEL * D_MODEL * 2;
    unsigned short* wkT = (unsigned short*)p; p += (size_t)D_MODEL * D_MODEL * 2;
    unsigned short* wvT = (unsigned short*)p; p += (size_t)D_MODEL * D_MODEL * 2;
    unsigned short* woT = (unsigned short*)p; p += (size_t)D_MODEL * D_MODEL * 2;
    unsigned short* qb  = (unsigned short*)p; p += (size_t)MROWS * D_MODEL * 2;
    unsigned short* kb  = (unsigned short*)p; p += (size_t)MROWS * D_MODEL * 2;
    unsigned short* vtb = (unsigned short*)p; p += (size_t)MROWS * D_MODEL * 2;
    unsigned short* ob  = (unsigned short*)p; p += (size_t)MROWS * D_MODEL * 2;
    float* accP = (float*)p;            p += (size_t)2 * QROWS * 64 * 4;   // 33.6 MB
    float* ml   = (float*)p;            p += (size_t)2 * QROWS * 2 * 4;    // 1 MB
    size_t need2 = (size_t)(p - (char*)d_ws);
    const int nsplit = (ws_size >= need2) ? 2 : 1;

    prep_kernel<<<5376, 256, 0, stream>>>(x, Wq, Wk, Wv, Wo,
                                          xb, wqT, wkT, wvT, woT, cosT, sinT);

    qkv_proj_kernel<<<dim3(MROWS / 128, D_MODEL / 64, 3), 256, 0, stream>>>(
        xb, wqT, wkT, wvT, bq, bk, bv, cosT, sinT, qb, kb, vtb);

    attn_mfma32_kernel<<<dim3(SEQ / 128, BHTOT, nsplit), 256, 0, stream>>>(
        qb, kb, vtb, ob, accP, ml, nsplit);

    if (nsplit == 2)
        combine2_kernel<<<(QROWS * 16) / 256, 256, 0, stream>>>(accP, ml, ob);

    outproj_kernel<<<dim3(MROWS / 128, D_MODEL / 64), 256, 0, stream>>>(ob, woT, bo, (float*)d_out);
}

// Round 17
// 140.212 us; speedup vs baseline: 1.0797x; 1.0797x over previous
//
#include <hip/hip_runtime.h>
#include <cmath>

#define D_MODEL  1024
#define NHEADS   16
#define DHEAD    64
#define BATCH    2
#define SEQ      2048
#define MROWS    (BATCH * SEQ)
#define HALF_DH  32
#define BHTOT    (BATCH * NHEADS)          // 32
#define QROWS    (BHTOT * SEQ)             // 65536

// softmax scale baked into Q at projection time: S' = (Q*SCQ)K^T is directly
// the exp2 argument;  exp2(S' - m') == softmax numerator (shift-invariant).
#define SCQ (0.125f * 1.44269504088896340736f)

typedef __attribute__((ext_vector_type(8))) short short8;    // 8 bf16 = 4 VGPRs
typedef __attribute__((ext_vector_type(4))) float f32x4;     // 16x16 C/D
typedef __attribute__((ext_vector_type(16))) float f32x16;   // 32x32 C/D

#define MFMA16(A,B,C) __builtin_amdgcn_mfma_f32_16x16x32_bf16(A,B,C,0,0,0)
#define MFMA32(A,B,C) __builtin_amdgcn_mfma_f32_32x32x16_bf16(A,B,C,0,0,0)

__device__ __forceinline__ unsigned short f2bf(float f) {
    unsigned int u = __float_as_uint(f);
    u += 0x7fffu + ((u >> 16) & 1u);
    return (unsigned short)(u >> 16);
}

__device__ __forceinline__ void gload_lds16(const void* g, void* l) {
    __builtin_amdgcn_global_load_lds(
        (const __attribute__((address_space(1))) unsigned int*)g,
        (__attribute__((address_space(3))) unsigned int*)l,
        16, 0, 0);
}

// ---------------------------------------------------------------------------
// K0: fused prep — blockIdx.x ranges (block-uniform branches):
//   [0,4096): x fp32->bf16 | [4096,5120): weight transpose | [5120,5376): RoPE
// ---------------------------------------------------------------------------
__global__ __launch_bounds__(256)
void prep_kernel(const float* __restrict__ x,
                 const float* __restrict__ Wq, const float* __restrict__ Wk,
                 const float* __restrict__ Wv, const float* __restrict__ Wo,
                 unsigned short* __restrict__ xb,
                 unsigned short* __restrict__ wqT, unsigned short* __restrict__ wkT,
                 unsigned short* __restrict__ wvT, unsigned short* __restrict__ woT,
                 float* __restrict__ cosT, float* __restrict__ sinT)
{
    __shared__ unsigned short T[64][68];
    const int bid = blockIdx.x;
    const int tid = threadIdx.x;

    if (bid < 4096) {                       // convert x -> bf16
        int i = bid * 256 + tid;
        float4 v = ((const float4*)x)[i];
        ushort4 o;
        o.x = f2bf(v.x); o.y = f2bf(v.y); o.z = f2bf(v.z); o.w = f2bf(v.w);
        ((ushort4*)xb)[i] = o;
    } else if (bid < 5120) {                // weight transpose
        int b2 = bid - 4096;
        int z  = b2 >> 8;
        int bx = (b2 & 255) >> 4;
        int by = b2 & 15;
        const float* W; unsigned short* Wt;
        switch (z) {
            case 0:  W = Wq; Wt = wqT; break;
            case 1:  W = Wk; Wt = wkT; break;
            case 2:  W = Wv; Wt = wvT; break;
            default: W = Wo; Wt = woT; break;
        }
        const int k0 = bx * 64, n0 = by * 64;
        const int r = tid >> 4, cq = tid & 15;
        #pragma unroll
        for (int p = 0; p < 4; ++p) {
            int kk = r + 16 * p;
            float4 vv = *(const float4*)&W[(size_t)(k0 + kk) * D_MODEL + n0 + cq * 4];
            T[cq * 4 + 0][kk] = f2bf(vv.x);
            T[cq * 4 + 1][kk] = f2bf(vv.y);
            T[cq * 4 + 2][kk] = f2bf(vv.z);
            T[cq * 4 + 3][kk] = f2bf(vv.w);
        }
        __syncthreads();
        #pragma unroll
        for (int p = 0; p < 4; ++p) {
            int n = r + 16 * p;
            ushort4 ov;
            ov.x = T[n][cq * 4 + 0]; ov.y = T[n][cq * 4 + 1];
            ov.z = T[n][cq * 4 + 2]; ov.w = T[n][cq * 4 + 3];
            *(ushort4*)&Wt[(size_t)(n0 + n) * D_MODEL + k0 + cq * 4] = ov;
        }
    } else {                                // RoPE tables
        int idx = (bid - 5120) * 256 + tid;
        int l = idx >> 5;
        int j = idx & 31;
        float inv = powf(10000.0f, -(float)(2 * j) / (float)DHEAD);
        float ang = (float)l * inv;
        cosT[idx] = cosf(ang);
        sinT[idx] = sinf(ang);
    }
}

// ---------------------------------------------------------------------------
// K3: fused QKV projection, BM=128 BN=64 BK=64 (R10/R12-proven tile).
// blockIdx.z: 0=q (RoPE, pre-scaled by SCQ), 1=k (RoPE),
//             2=v (LDS-transpose -> Vt[bh][d][l]).
// ---------------------------------------------------------------------------
__global__ __launch_bounds__(256)
void qkv_proj_kernel(const unsigned short* __restrict__ A,
                     const unsigned short* __restrict__ wqT, const unsigned short* __restrict__ wkT,
                     const unsigned short* __restrict__ wvT,
                     const float* __restrict__ bq, const float* __restrict__ bk,
                     const float* __restrict__ bv,
                     const float* __restrict__ cosT, const float* __restrict__ sinT,
                     unsigned short* __restrict__ qb, unsigned short* __restrict__ kb,
                     unsigned short* __restrict__ vtb)
{
    __shared__ unsigned short SMEM[128 * 64 + 64 * 64];   // As(16KB) + Bs(8KB)
    unsigned short* As = SMEM;
    unsigned short* Bs = SMEM + 128 * 64;

    const int z = blockIdx.z;
    const unsigned short* Bt = (z == 0) ? wqT : (z == 1) ? wkT : wvT;
    const float* bias = (z == 0) ? bq : (z == 1) ? bk : bv;

    const int tid = threadIdx.x;
    const int w = tid >> 6, ln = tid & 63;
    const int c = ln & 15, g = ln >> 4;
    const int bm = blockIdx.x * 128, bn = blockIdx.y * 64;
    const int srow = ln >> 3, sblk = ln & 7;

    f32x4 acc[2][4];
    #pragma unroll
    for (int mi = 0; mi < 2; ++mi)
        #pragma unroll
        for (int ni = 0; ni < 4; ++ni) acc[mi][ni] = (f32x4){0.f, 0.f, 0.f, 0.f};

    for (int k0 = 0; k0 < D_MODEL; k0 += 64) {
        __syncthreads();
        #pragma unroll
        for (int i = 0; i < 4; ++i) {
            int chunk = w * 4 + i;
            int row = chunk * 8 + srow;
            int gcol = (sblk ^ (row & 7)) * 8;
            gload_lds16(&A[(size_t)(bm + row) * D_MODEL + k0 + gcol], &As[chunk * 512]);
        }
        #pragma unroll
        for (int i = 0; i < 2; ++i) {
            int chunk = w * 2 + i;
            int row = chunk * 8 + srow;
            int gcol = (sblk ^ (row & 7)) * 8;
            gload_lds16(&Bt[(size_t)(bn + row) * D_MODEL + k0 + gcol], &Bs[chunk * 512]);
        }
        __syncthreads();

        #pragma unroll
        for (int ks = 0; ks < 2; ++ks) {
            const int koff = (ks * 32 + g * 8) ^ ((c & 7) * 8);
            short8 af[2];
            #pragma unroll
            for (int mi = 0; mi < 2; ++mi)
                af[mi] = *(const short8*)&As[(w * 32 + mi * 16 + c) * 64 + koff];
            #pragma unroll
            for (int ni = 0; ni < 4; ++ni) {
                short8 bfr = *(const short8*)&Bs[(ni * 16 + c) * 64 + koff];
                #pragma unroll
                for (int mi = 0; mi < 2; ++mi)
                    acc[mi][ni] = MFMA16(af[mi], bfr, acc[mi][ni]);
            }
        }
    }

    float bv4[4];
    #pragma unroll
    for (int ni = 0; ni < 4; ++ni) bv4[ni] = bias[bn + ni * 16 + c];

    if (z < 2) {
        unsigned short* op = z ? kb : qb;
        const float qscale = (z == 0) ? SCQ : 1.0f;   // bake softmax scale into q
        const int hy = blockIdx.y;                    // head (BN == DHEAD)
        #pragma unroll
        for (int mi = 0; mi < 2; ++mi) {
            #pragma unroll
            for (int r = 0; r < 4; ++r) {
                const int m = bm + w * 32 + mi * 16 + g * 4 + r;
                const int b = m >> 11, ll = m & (SEQ - 1);
                float v[4];
                #pragma unroll
                for (int ni = 0; ni < 4; ++ni) v[ni] = acc[mi][ni][r] + bv4[ni];
                #pragma unroll
                for (int ni = 0; ni < 2; ++ni) {      // RoPE
                    int d = ni * 16 + c;
                    float co = cosT[ll * HALF_DH + d];
                    float si = sinT[ll * HALF_DH + d];
                    float lo = v[ni], hi = v[ni + 2];
                    v[ni]     = lo * co - hi * si;
                    v[ni + 2] = hi * co + lo * si;
                }
                unsigned short* dst = op + ((size_t)(b * NHEADS + hy) * SEQ + ll) * DHEAD;
                #pragma unroll
                for (int ni = 0; ni < 4; ++ni) dst[ni * 16 + c] = f2bf(v[ni] * qscale);
            }
        }
    } else {
        // v: transpose 128(m) x 64(d) tile -> Vt[bh][d][l] via LDS (overlay SMEM)
        unsigned short (*T)[136] = (unsigned short(*)[136])SMEM;   // 64 x 136 shorts
        __syncthreads();                               // all MFMA LDS reads done
        #pragma unroll
        for (int mi = 0; mi < 2; ++mi)
            #pragma unroll
            for (int r = 0; r < 4; ++r)
                #pragma unroll
                for (int ni = 0; ni < 4; ++ni)
                    T[ni * 16 + c][w * 32 + mi * 16 + g * 4 + r] = f2bf(acc[mi][ni][r] + bv4[ni]);
        __syncthreads();
        const int b  = bm >> 11;
        const int l0 = bm & (SEQ - 1);                 // per-batch seq offset
        const int bh = b * NHEADS + blockIdx.y;
        unsigned short* Vo = vtb + (size_t)bh * DHEAD * SEQ;
        #pragma unroll
        for (int it = 0; it < 4; ++it) {
            int row  = (tid >> 4) + it * 16;           // d
            int col8 = tid & 15;                       // 8-short chunk along m
            uint4 val = *(const uint4*)&T[row][col8 * 8];
            *(uint4*)&Vo[(size_t)row * SEQ + l0 + col8 * 8] = val;
        }
    }
}

// ---------------------------------------------------------------------------
// K4: out-projection GEMM, BM=128 BN=64 (bf16 A=ob, fp32 out) (R10-proven)
// ---------------------------------------------------------------------------
__global__ __launch_bounds__(256)
void outproj_kernel(const unsigned short* __restrict__ A, const unsigned short* __restrict__ Bt,
                    const float* __restrict__ bias, float* __restrict__ out)
{
    __shared__ unsigned short As[128 * 64];
    __shared__ unsigned short Bs[64 * 64];
    const int tid = threadIdx.x;
    const int w = tid >> 6, ln = tid & 63;
    const int c = ln & 15, g = ln >> 4;
    const int bm = blockIdx.x * 128, bn = blockIdx.y * 64;
    const int srow = ln >> 3, sblk = ln & 7;

    f32x4 acc[2][4];
    #pragma unroll
    for (int mi = 0; mi < 2; ++mi)
        #pragma unroll
        for (int ni = 0; ni < 4; ++ni) acc[mi][ni] = (f32x4){0.f, 0.f, 0.f, 0.f};

    for (int k0 = 0; k0 < D_MODEL; k0 += 64) {
        __syncthreads();
        #pragma unroll
        for (int i = 0; i < 4; ++i) {
            int chunk = w * 4 + i;
            int row = chunk * 8 + srow;
            int gcol = (sblk ^ (row & 7)) * 8;
            gload_lds16(&A[(size_t)(bm + row) * D_MODEL + k0 + gcol], &As[chunk * 512]);
        }
        #pragma unroll
        for (int i = 0; i < 2; ++i) {
            int chunk = w * 2 + i;
            int row = chunk * 8 + srow;
            int gcol = (sblk ^ (row & 7)) * 8;
            gload_lds16(&Bt[(size_t)(bn + row) * D_MODEL + k0 + gcol], &Bs[chunk * 512]);
        }
        __syncthreads();

        #pragma unroll
        for (int ks = 0; ks < 2; ++ks) {
            const int koff = (ks * 32 + g * 8) ^ ((c & 7) * 8);
            short8 af[2];
            #pragma unroll
            for (int mi = 0; mi < 2; ++mi)
                af[mi] = *(const short8*)&As[(w * 32 + mi * 16 + c) * 64 + koff];
            #pragma unroll
            for (int ni = 0; ni < 4; ++ni) {
                short8 bfr = *(const short8*)&Bs[(ni * 16 + c) * 64 + koff];
                #pragma unroll
                for (int mi = 0; mi < 2; ++mi)
                    acc[mi][ni] = MFMA16(af[mi], bfr, acc[mi][ni]);
            }
        }
    }

    float bv4[4];
    #pragma unroll
    for (int ni = 0; ni < 4; ++ni) bv4[ni] = bias[bn + ni * 16 + c];
    #pragma unroll
    for (int mi = 0; mi < 2; ++mi)
        #pragma unroll
        for (int r = 0; r < 4; ++r) {
            const int m = bm + w * 32 + mi * 16 + g * 4 + r;
            #pragma unroll
            for (int ni = 0; ni < 4; ++ni)
                out[(size_t)m * D_MODEL + bn + ni * 16 + c] = acc[mi][ni][r] + bv4[ni];
        }
}

// ---------------------------------------------------------------------------
// K5: MFMA flash attention (R13-proven: 4-wave blocks, QBLK=128, pre-scaled Q,
// ones-MFMA row-sum, max3 tree, hoisted offsets, defer-max THR=4,
// global_load_lds staging — R16 proved reg-staging is slower despite its
// bank-conflict-free reads). Split-K over KV via grid.z.
// ---------------------------------------------------------------------------
__global__ __launch_bounds__(256, 4)
void attn_mfma32_kernel(const unsigned short* __restrict__ Q, const unsigned short* __restrict__ K,
                        const unsigned short* __restrict__ Vt, unsigned short* __restrict__ O,
                        float* __restrict__ accP, float* __restrict__ ml, int nsplit)
{
    __shared__ unsigned short Ks[2][64 * 64];
    __shared__ unsigned short Vs[2][64 * 64];
    const int tid = threadIdx.x;
    const int w = tid >> 6, ln = tid & 63;
    const int ql = ln & 31;
    const int h  = ln >> 5;
    const int bh = blockIdx.y;
    const int q  = blockIdx.x * 128 + w * 32 + ql;
    const int split = blockIdx.z;
    const int ntile = SEQ / (64 * nsplit);
    const int kt0 = split * (SEQ / nsplit);
    const int srow = ln >> 3, sblk = ln & 7;

    const unsigned short* Qb = Q  + (size_t)bh * SEQ * DHEAD;
    const unsigned short* Kb = K  + (size_t)bh * SEQ * DHEAD;
    const unsigned short* Vb = Vt + (size_t)bh * DHEAD * SEQ;

    short8 qf[4];
    #pragma unroll
    for (int dk = 0; dk < 4; ++dk)
        qf[dk] = *(const short8*)&Qb[(size_t)q * DHEAD + dk * 16 + h * 8];

    short8 onesF;
    #pragma unroll
    for (int i = 0; i < 8; ++i) onesF[i] = (short)0x3F80;

    int offk[4];
    #pragma unroll
    for (int t = 0; t < 4; ++t) offk[t] = ((2 * t + h) ^ (ql & 7)) * 8;
    const int rA = ql * 64, rB = (32 + ql) * 64;

    f32x16 accO0, accO1, accS;
    #pragma unroll
    for (int r = 0; r < 16; ++r) { accO0[r] = 0.f; accO1[r] = 0.f; accS[r] = 0.f; }
    float mst = -1e30f;

    #pragma unroll
    for (int i = 0; i < 2; ++i) {
        int chunk = w * 2 + i;
        int row = chunk * 8 + srow;
        int gcol = (sblk ^ (row & 7)) * 8;
        gload_lds16(&Kb[(size_t)(kt0 + row) * DHEAD + gcol], &Ks[0][chunk * 512]);
        gload_lds16(&Vb[(size_t)row * SEQ + kt0 + gcol],     &Vs[0][chunk * 512]);
    }
    __syncthreads();

    int cur = 0;
    for (int it = 0; it < ntile; ++it) {
        const int kt = kt0 + it * 64;
        if (it + 1 < ntile) {
            #pragma unroll
            for (int i = 0; i < 2; ++i) {
                int chunk = w * 2 + i;
                int row = chunk * 8 + srow;
                int gcol = (sblk ^ (row & 7)) * 8;
                gload_lds16(&Kb[(size_t)(kt + 64 + row) * DHEAD + gcol], &Ks[cur ^ 1][chunk * 512]);
                gload_lds16(&Vb[(size_t)row * SEQ + kt + 64 + gcol],     &Vs[cur ^ 1][chunk * 512]);
            }
        }

        // S = K Q^T   (already in exp2-argument units)
        f32x16 s0, s1;
        #pragma unroll
        for (int r = 0; r < 16; ++r) { s0[r] = 0.f; s1[r] = 0.f; }
        #pragma unroll
        for (int dk = 0; dk < 4; ++dk) {
            short8 kf0 = *(const short8*)&Ks[cur][rA + offk[dk]];
            short8 kf1 = *(const short8*)&Ks[cur][rB + offk[dk]];
            s0 = MFMA32(kf0, qf[dk], s0);
            s1 = MFMA32(kf1, qf[dk], s1);
        }

        // row max: max3-fused triplet tree + one cross-half shfl
        float a0 = fmaxf(fmaxf(s0[0], s0[1]), s0[2]);
        float a1 = fmaxf(fmaxf(s0[3], s0[4]), s0[5]);
        float a2 = fmaxf(fmaxf(s0[6], s0[7]), s0[8]);
        float a3 = fmaxf(fmaxf(s0[9], s0[10]), s0[11]);
        float a4 = fmaxf(fmaxf(s0[12], s0[13]), s0[14]);
        float a5 = fmaxf(fmaxf(s0[15], s1[0]), s1[1]);
        float a6 = fmaxf(fmaxf(s1[2], s1[3]), s1[4]);
        float a7 = fmaxf(fmaxf(s1[5], s1[6]), s1[7]);
        float a8 = fmaxf(fmaxf(s1[8], s1[9]), s1[10]);
        float a9 = fmaxf(fmaxf(s1[11], s1[12]), s1[13]);
        float aA = fmaxf(s1[14], s1[15]);
        float b0 = fmaxf(fmaxf(a0, a1), a2);
        float b1 = fmaxf(fmaxf(a3, a4), a5);
        float b2 = fmaxf(fmaxf(a6, a7), a8);
        float b3 = fmaxf(a9, aA);
        float mx = fmaxf(fmaxf(fmaxf(b0, b1), b2), b3);
        mx = fmaxf(mx, __shfl_xor(mx, 32));

        // T13 defer-max: rescale only if some lane's growth exceeds THR
        if (!__all(mx - mst <= 4.0f)) {
            const float mn = fmaxf(mst, mx);
            const float rsc = exp2f(mst - mn);
            #pragma unroll
            for (int r = 0; r < 16; ++r) { accO0[r] *= rsc; accO1[r] *= rsc; }
            accS[0] *= rsc;
            mst = mn;
        }

        // P = exp2(S - mst)
        #pragma unroll
        for (int r = 0; r < 16; ++r) {
            s0[r] = exp2f(s0[r] - mst);
            s1[r] = exp2f(s1[r] - mst);
        }

        // repack P -> 4 bf16 B-fragments (cvt_pk + permlane32_swap, verified R5)
        short8 pf[4];
        #define REPACK_T(T, SV)                                                          \
        {                                                                                \
            unsigned int wA0, wA1, wB0, wB1;                                             \
            asm("v_cvt_pk_bf16_f32 %0, %1, %2" : "=v"(wA0)                               \
                : "v"((SV)[8 * ((T) & 1) + 0]), "v"((SV)[8 * ((T) & 1) + 1]));           \
            asm("v_cvt_pk_bf16_f32 %0, %1, %2" : "=v"(wA1)                               \
                : "v"((SV)[8 * ((T) & 1) + 2]), "v"((SV)[8 * ((T) & 1) + 3]));           \
            asm("v_cvt_pk_bf16_f32 %0, %1, %2" : "=v"(wB0)                               \
                : "v"((SV)[8 * ((T) & 1) + 4]), "v"((SV)[8 * ((T) & 1) + 5]));           \
            asm("v_cvt_pk_bf16_f32 %0, %1, %2" : "=v"(wB1)                               \
                : "v"((SV)[8 * ((T) & 1) + 6]), "v"((SV)[8 * ((T) & 1) + 7]));           \
            asm("v_permlane32_swap_b32 %0, %1" : "+v"(wA0), "+v"(wB0));                  \
            asm("v_permlane32_swap_b32 %0, %1" : "+v"(wA1), "+v"(wB1));                  \
            union { short8 v; unsigned int u[4]; } tmp;                                  \
            tmp.u[0] = wA0; tmp.u[1] = wA1; tmp.u[2] = wB0; tmp.u[3] = wB1;              \
            pf[T] = tmp.v;                                                               \
        }
        REPACK_T(0, s0) REPACK_T(1, s0) REPACK_T(2, s1) REPACK_T(3, s1)
        #undef REPACK_T

        // O^T += V^T P, and row-sums via ones-A MFMA (accS[0] = l)
        #pragma unroll
        for (int t = 0; t < 4; ++t) {
            short8 vf0 = *(const short8*)&Vs[cur][rA + offk[t]];
            short8 vf1 = *(const short8*)&Vs[cur][rB + offk[t]];
            accS  = MFMA32(onesF, pf[t], accS);
            accO0 = MFMA32(vf0, pf[t], accO0);
            accO1 = MFMA32(vf1, pf[t], accO1);
        }

        __syncthreads();
        cur ^= 1;
    }

    const float accL = accS[0];
    if (nsplit == 1) {
        const int b = bh >> 4, hh = bh & 15;
        const float inv = 1.0f / accL;
        unsigned short* dst = O + ((size_t)(b * SEQ + q)) * D_MODEL + hh * DHEAD;
        #define EPI(ACC, DC)                                                             \
        {                                                                                \
            _Pragma("unroll")                                                            \
            for (int rq = 0; rq < 4; ++rq) {                                             \
                float a0 = (ACC)[4 * rq + 0] * inv, a1 = (ACC)[4 * rq + 1] * inv;        \
                float a2 = (ACC)[4 * rq + 2] * inv, a3 = (ACC)[4 * rq + 3] * inv;        \
                unsigned int p0, p1;                                                     \
                asm("v_cvt_pk_bf16_f32 %0, %1, %2" : "=v"(p0) : "v"(a0), "v"(a1));       \
                asm("v_cvt_pk_bf16_f32 %0, %1, %2" : "=v"(p1) : "v"(a2), "v"(a3));       \
                uint2 pk; pk.x = p0; pk.y = p1;                                          \
                *(uint2*)(dst + 32 * (DC) + 8 * rq + 4 * h) = pk;                        \
            }                                                                            \
        }
        EPI(accO0, 0) EPI(accO1, 1)
        #undef EPI
    } else {
        float* base = accP + ((size_t)(split * BHTOT + bh) * SEQ + q) * 64;
        #pragma unroll
        for (int rq = 0; rq < 4; ++rq) {
            float4 v0, v1;
            v0.x = accO0[4 * rq + 0]; v0.y = accO0[4 * rq + 1];
            v0.z = accO0[4 * rq + 2]; v0.w = accO0[4 * rq + 3];
            v1.x = accO1[4 * rq + 0]; v1.y = accO1[4 * rq + 1];
            v1.z = accO1[4 * rq + 2]; v1.w = accO1[4 * rq + 3];
            *(float4*)&base[8 * rq + 4 * h]      = v0;
            *(float4*)&base[32 + 8 * rq + 4 * h] = v1;
        }
        if (h == 0) {
            float2 v; v.x = mst; v.y = accL;
            ((float2*)ml)[(size_t)(split * BHTOT + bh) * SEQ + q] = v;
        }
    }
}

// ---------------------------------------------------------------------------
// K6: combine the 2 split-K partials (exact fp32 online-softmax merge;
// m values are already exp2-argument units — no SC)
// ---------------------------------------------------------------------------
__global__ __launch_bounds__(256)
void combine2_kernel(const float* __restrict__ accP, const float* __restrict__ ml,
                     unsigned short* __restrict__ ob)
{
    int t = blockIdx.x * 256 + threadIdx.x;        // over QROWS*16
    int d4  = (t & 15) * 4;
    int bhq = t >> 4;
    const float2* ML = (const float2*)ml;
    float2 m0 = ML[bhq];
    float2 m1 = ML[(size_t)QROWS + bhq];
    float M  = fmaxf(m0.x, m1.x);
    float w0 = exp2f(m0.x - M);
    float w1 = exp2f(m1.x - M);
    float inv = 1.0f / (w0 * m0.y + w1 * m1.y);
    float4 a0 = *(const float4*)&accP[(size_t)bhq * 64 + d4];
    float4 a1 = *(const float4*)&accP[(size_t)QROWS * 64 + (size_t)bhq * 64 + d4];
    float o0 = (a0.x * w0 + a1.x * w1) * inv;
    float o1 = (a0.y * w0 + a1.y * w1) * inv;
    float o2 = (a0.z * w0 + a1.z * w1) * inv;
    float o3 = (a0.w * w0 + a1.w * w1) * inv;
    int bh = bhq >> 11, q = bhq & (SEQ - 1);
    int b = bh >> 4, hh = bh & 15;
    ushort4 ov;
    ov.x = f2bf(o0); ov.y = f2bf(o1); ov.z = f2bf(o2); ov.w = f2bf(o3);
    *(ushort4*)&ob[((size_t)(b * SEQ + q)) * D_MODEL + hh * DHEAD + d4] = ov;
}

// ---------------------------------------------------------------------------
extern "C" void kernel_launch(void* const* d_in, const int* in_sizes, int n_in,
                              void* d_out, int out_size, void* d_ws, size_t ws_size,
                              hipStream_t stream)
{
    const float* x  = (const float*)d_in[0];
    const float* Wq = (const float*)d_in[1];
    const float* bq = (const float*)d_in[2];
    const float* Wk = (const float*)d_in[3];
    const float* bk = (const float*)d_in[4];
    const float* Wv = (const float*)d_in[5];
    const float* bv = (const float*)d_in[6];
    const float* Wo = (const float*)d_in[7];
    const float* bo = (const float*)d_in[8];

    // workspace carve
    char* p = (char*)d_ws;
    float* cosT = (float*)p;            p += (size_t)SEQ * HALF_DH * 4;
    float* sinT = (float*)p;            p += (size_t)SEQ * HALF_DH * 4;
    unsigned short* xb  = (unsigned short*)p; p += (size_t)MROWS * D_MODEL * 2;
    unsigned short* wqT = (unsigned short*)p; p += (size_t)D_MODEL * D_MODEL * 2;
    unsigned short* wkT = (unsigned short*)p; p += (size_t)D_MODEL * D_MODEL * 2;
    unsigned short* wvT = (unsigned short*)p; p += (size_t)D_MODEL * D_MODEL * 2;
    unsigned short* woT = (unsigned short*)p; p += (size_t)D_MODEL * D_MODEL * 2;
    unsigned short* qb  = (unsigned short*)p; p += (size_t)MROWS * D_MODEL * 2;
    unsigned short* kb  = (unsigned short*)p; p += (size_t)MROWS * D_MODEL * 2;
    unsigned short* vtb = (unsigned short*)p; p += (size_t)MROWS * D_MODEL * 2;
    unsigned short* ob  = (unsigned short*)p; p += (size_t)MROWS * D_MODEL * 2;
    float* accP = (float*)p;            p += (size_t)2 * QROWS * 64 * 4;   // 33.6 MB
    float* ml   = (float*)p;            p += (size_t)2 * QROWS * 2 * 4;    // 1 MB
    size_t need2 = (size_t)(p - (char*)d_ws);
    const int nsplit = (ws_size >= need2) ? 2 : 1;

    prep_kernel<<<5376, 256, 0, stream>>>(x, Wq, Wk, Wv, Wo,
                                          xb, wqT, wkT, wvT, woT, cosT, sinT);

    qkv_proj_kernel<<<dim3(MROWS / 128, D_MODEL / 64, 3), 256, 0, stream>>>(
        xb, wqT, wkT, wvT, bq, bk, bv, cosT, sinT, qb, kb, vtb);

    attn_mfma32_kernel<<<dim3(SEQ / 128, BHTOT, nsplit), 256, 0, stream>>>(
        qb, kb, vtb, ob, accP, ml, nsplit);

    if (nsplit == 2)
        combine2_kernel<<<(QROWS * 16) / 256, 256, 0, stream>>>(accP, ml, ob);

    outproj_kernel<<<dim3(MROWS / 128, D_MODEL / 64), 256, 0, stream>>>(ob, woT, bo, (float*)d_out);
}